// Round 1
// baseline (5686.363 us; speedup 1.0000x reference)
//
#include <hip/hip_runtime.h>
#include <cmath>

// Sinkhorn distance, B=8, P1=P2=2048, dim=3, EPS=1, MAX_ITER=100, THRESH=1e-9
// Outputs (flat, in return order): cost[8], pi[8*2048*2048], D[8*2048*2048]

constexpr int BATCH = 8;
constexpr int P = 2048;
constexpr int MAX_ITER = 100;

__global__ __launch_bounds__(256) void sk_init(float* __restrict__ u, float* __restrict__ v,
                                               unsigned* __restrict__ errU, unsigned* __restrict__ errV,
                                               int* __restrict__ flag, float v0)
{
    int idx = blockIdx.x * 256 + threadIdx.x;
    u[idx] = 0.0f;
    v[idx] = v0;
    if (blockIdx.x == 0) {
        if (threadIdx.x < BATCH) { errU[threadIdx.x] = 0u; errV[threadIdx.x] = 0u; }
        if (threadIdx.x == 0) *flag = 0;
    }
}

// One half-update of Sinkhorn: dual_out[b,i] = logw - log( sum_j exp(dual_red[b,j] - dist(Pout[b,i], Pred[b,j])) )
// Block: 256 threads = 4 waves; each wave owns 4 output rows; reduction side staged in LDS as float4{p0,p1,p2,dual}.
__global__ __launch_bounds__(256) void sk_pass(const float* __restrict__ Pout,
                                               const float* __restrict__ Pred,
                                               const float* __restrict__ dual_red,
                                               float* __restrict__ dual_out,
                                               float logw,
                                               unsigned* __restrict__ err_bits,
                                               const int* __restrict__ flag)
{
    if (*flag) return;
    __shared__ float4 sh[P];          // 32 KiB
    __shared__ float werr[4];

    const int b = blockIdx.x >> 7;                 // 128 blocks per batch
    const int rowbase = (blockIdx.x & 127) << 4;   // 16 rows per block

    const float* pr = Pred + (size_t)b * P * 3;
    const float* dr = dual_red + (size_t)b * P;
    for (int j = threadIdx.x; j < P; j += 256) {
        sh[j] = make_float4(pr[3*j], pr[3*j+1], pr[3*j+2], dr[j]);
    }
    __syncthreads();

    const int wave = threadIdx.x >> 6;
    const int lane = threadIdx.x & 63;
    const int i0 = rowbase + wave * 4;

    const float* po = Pout + ((size_t)b * P + i0) * 3;
    float a0[4], a1[4], a2[4];
    #pragma unroll
    for (int r = 0; r < 4; ++r) {
        a0[r] = po[3*r + 0];
        a1[r] = po[3*r + 1];
        a2[r] = po[3*r + 2];
    }

    float s[4] = {0.f, 0.f, 0.f, 0.f};
    for (int j = lane; j < P; j += 64) {
        float4 q = sh[j];
        #pragma unroll
        for (int r = 0; r < 4; ++r) {
            float dx = a0[r] - q.x;
            float dy = a1[r] - q.y;
            float dz = a2[r] - q.z;
            float d = sqrtf(fmaf(dx, dx, fmaf(dy, dy, dz * dz)));
            s[r] += __expf(q.w - d);   // no max-subtraction needed: args in [-30, 0]
        }
    }

    #pragma unroll
    for (int r = 0; r < 4; ++r) {
        #pragma unroll
        for (int off = 32; off; off >>= 1) s[r] += __shfl_xor(s[r], off);
    }

    if (lane == 0) {
        float em = 0.f;
        #pragma unroll
        for (int r = 0; r < 4; ++r) {
            float un = logw - __logf(s[r]);
            float* dst = dual_out + (size_t)b * P + i0 + r;
            float old = *dst;
            em = fmaxf(em, fabsf(old - un));
            *dst = un;
        }
        werr[wave] = em;
    }
    __syncthreads();
    if (threadIdx.x == 0) {
        float m = fmaxf(fmaxf(werr[0], werr[1]), fmaxf(werr[2], werr[3]));
        atomicMax(err_bits + b, __float_as_uint(m));   // valid: values >= 0
    }
}

__global__ void sk_check(unsigned* __restrict__ errU, unsigned* __restrict__ errV,
                         int* __restrict__ flag)
{
    if (*flag) return;
    if (threadIdx.x == 0) {
        float eu = 0.f, ev = 0.f;
        for (int b = 0; b < BATCH; ++b) {
            eu += __uint_as_float(errU[b]);
            ev += __uint_as_float(errV[b]);
            errU[b] = 0u;
            errV[b] = 0u;
        }
        eu *= (1.0f / BATCH);
        ev *= (1.0f / BATCH);
        if (eu < 1e-9f && ev < 1e-9f) *flag = 1;
    }
}

// Final: D, pi = exp(D + u + v)  (faithful to reference's +D), rowsum of pi*D
__global__ __launch_bounds__(256) void sk_final(const float* __restrict__ x, const float* __restrict__ y,
                                                const float* __restrict__ u, const float* __restrict__ v,
                                                float* __restrict__ outPi, float* __restrict__ outD,
                                                float* __restrict__ rowsum)
{
    const int row = blockIdx.x;        // b*P + i
    const int b = row >> 11;
    const float xi0 = x[3*row + 0];
    const float xi1 = x[3*row + 1];
    const float xi2 = x[3*row + 2];
    const float ui = u[row];
    const float* yb = y + (size_t)b * P * 3;
    const float* vb = v + (size_t)b * P;
    const size_t base = (size_t)row * P;

    float acc = 0.f;
    for (int j = threadIdx.x; j < P; j += 256) {
        float dx = xi0 - yb[3*j + 0];
        float dy = xi1 - yb[3*j + 1];
        float dz = xi2 - yb[3*j + 2];
        float d = sqrtf(fmaf(dx, dx, fmaf(dy, dy, dz * dz)));
        float pival = __expf(d + ui + vb[j]);
        outD[base + j] = d;
        outPi[base + j] = pival;
        acc += pival * d;
    }
    #pragma unroll
    for (int off = 32; off; off >>= 1) acc += __shfl_xor(acc, off);
    __shared__ float sred[4];
    if ((threadIdx.x & 63) == 0) sred[threadIdx.x >> 6] = acc;
    __syncthreads();
    if (threadIdx.x == 0) rowsum[row] = sred[0] + sred[1] + sred[2] + sred[3];
}

__global__ __launch_bounds__(256) void sk_cost(const float* __restrict__ rowsum, float* __restrict__ cost)
{
    const int b = blockIdx.x;
    float acc = 0.f;
    for (int i = threadIdx.x; i < P; i += 256) acc += rowsum[b * P + i];
    #pragma unroll
    for (int off = 32; off; off >>= 1) acc += __shfl_xor(acc, off);
    __shared__ float sred[4];
    if ((threadIdx.x & 63) == 0) sred[threadIdx.x >> 6] = acc;
    __syncthreads();
    if (threadIdx.x == 0) cost[b] = sred[0] + sred[1] + sred[2] + sred[3];
}

extern "C" void kernel_launch(void* const* d_in, const int* in_sizes, int n_in,
                              void* d_out, int out_size, void* d_ws, size_t ws_size,
                              hipStream_t stream)
{
    const float* x = (const float*)d_in[0];
    const float* y = (const float*)d_in[1];

    float* out  = (float*)d_out;
    float* cost = out;                                 // [8]
    float* pi   = out + BATCH;                         // [8*2048*2048]
    float* Dm   = pi + (size_t)BATCH * P * P;          // [8*2048*2048]

    float* u      = (float*)d_ws;                      // [8*2048]
    float* v      = u + BATCH * P;                     // [8*2048]
    float* rowsum = v + BATCH * P;                     // [8*2048]
    unsigned* errU = (unsigned*)(rowsum + BATCH * P);  // [8]
    unsigned* errV = errU + BATCH;                     // [8]
    int* flag      = (int*)(errV + BATCH);             // [1]

    const float logw = logf(1.0f / P);   // log_wx == log_wy (P1==P2 -> scale factor 1)

    sk_init<<<BATCH * P / 256, 256, 0, stream>>>(u, v, errU, errV, flag, logw);

    for (int it = 0; it < MAX_ITER; ++it) {
        // u update: output side = x rows, reduce over y/v
        sk_pass<<<BATCH * P / 16, 256, 0, stream>>>(x, y, v, u, logw, errU, flag);
        // v update: output side = y cols, reduce over x/u (just-written)
        sk_pass<<<BATCH * P / 16, 256, 0, stream>>>(y, x, u, v, logw, errV, flag);
        sk_check<<<1, 64, 0, stream>>>(errU, errV, flag);
    }

    sk_final<<<BATCH * P, 256, 0, stream>>>(x, y, u, v, pi, Dm, rowsum);
    sk_cost<<<BATCH, 256, 0, stream>>>(rowsum, cost);
}

// Round 2
// 3006.193 us; speedup vs baseline: 1.8915x; 1.8915x over previous
//
#include <hip/hip_runtime.h>
#include <cmath>

// Sinkhorn distance, B=8, P1=P2=2048, dim=3, EPS=1, MAX_ITER=100, THRESH=1e-9
// Outputs (flat, in return order): cost[8], pi[8*2048*2048], D[8*2048*2048]
//
// Key identities used:
//  - Loop works in log2 space: coords & duals pre-scaled by log2(e), so
//    exp(v - d) == exp2(v' - d') with d' = sqrt of scaled-coord squared dist.
//  - THRESH=1e-9 < f32 ulp of u,v (~5e-7) => convergence <=> bitwise fixed
//    point => running all 100 iterations is exactly equivalent to early stop.

constexpr int BATCH = 8;
constexpr int P = 2048;
constexpr int MAX_ITER = 100;

#define LOG2E 1.44269504088896340736f
#define LN2   0.69314718055994530942f

// Pack pre-scaled coords into float4 (for b128 LDS staging) and init duals.
__global__ __launch_bounds__(256) void sk_prep(const float* __restrict__ x,
                                               const float* __restrict__ y,
                                               float4* __restrict__ xs,
                                               float4* __restrict__ ys,
                                               float* __restrict__ u,
                                               float* __restrict__ v,
                                               float v0)
{
    int idx = blockIdx.x * 256 + threadIdx.x;   // 0 .. BATCH*P-1
    u[idx] = 0.0f;
    v[idx] = v0;
    xs[idx] = make_float4(LOG2E * x[3*idx], LOG2E * x[3*idx+1], LOG2E * x[3*idx+2], 0.f);
    ys[idx] = make_float4(LOG2E * y[3*idx], LOG2E * y[3*idx+1], LOG2E * y[3*idx+2], 0.f);
}

// One half-update: dual_out[b,i] = logw - ln( sum_j exp2(v'_j - d'_ij) )
// 256 thr = 4 waves; each wave owns 4 output rows; reduce side staged in LDS.
__global__ __launch_bounds__(256) void sk_pass(const float4* __restrict__ PoutS,
                                               const float4* __restrict__ PredS,
                                               const float* __restrict__ dual_red,
                                               float* __restrict__ dual_out,
                                               float logw)
{
    __shared__ float4 sh[P];          // {q0', q1', q2', v'_j}  (32 KiB)

    const int b = blockIdx.x >> 7;                 // 128 blocks per batch
    const int rowbase = (blockIdx.x & 127) << 4;   // 16 rows per block

    const float4* pr = PredS + (size_t)b * P;
    const float* dr = dual_red + (size_t)b * P;
    for (int j = threadIdx.x; j < P; j += 256) {
        float4 c = pr[j];
        c.w = LOG2E * dr[j];
        sh[j] = c;
    }
    __syncthreads();

    const int wave = threadIdx.x >> 6;
    const int lane = threadIdx.x & 63;
    const int i0 = rowbase + wave * 4;

    const float4* po = PoutS + (size_t)b * P + i0;
    float a0[4], a1[4], a2[4];
    #pragma unroll
    for (int r = 0; r < 4; ++r) {
        float4 c = po[r];
        a0[r] = c.x; a1[r] = c.y; a2[r] = c.z;
    }

    float s[4] = {0.f, 0.f, 0.f, 0.f};
    for (int j = lane; j < P; j += 64) {
        float4 q = sh[j];
        #pragma unroll
        for (int r = 0; r < 4; ++r) {
            float dx = a0[r] - q.x;
            float dy = a1[r] - q.y;
            float dz = a2[r] - q.z;
            float r2 = fmaf(dx, dx, fmaf(dy, dy, dz * dz));
            float d = __builtin_amdgcn_sqrtf(r2);          // raw v_sqrt_f32
            s[r] += __builtin_amdgcn_exp2f(q.w - d);       // raw v_exp_f32
        }
    }

    #pragma unroll
    for (int r = 0; r < 4; ++r) {
        #pragma unroll
        for (int off = 32; off; off >>= 1) s[r] += __shfl_xor(s[r], off);
    }

    if (lane == 0) {
        #pragma unroll
        for (int r = 0; r < 4; ++r) {
            // ln(s) = LN2 * log2(s)
            dual_out[(size_t)b * P + i0 + r] = logw - LN2 * __builtin_amdgcn_logf(s[r]);
        }
    }
}

// Final: D, pi = exp(D + u + v) (faithful to reference's +D), rowsum of pi*D.
// One block per output row; float4 loads/stores (write-bound: 268 MB).
__global__ __launch_bounds__(256) void sk_final(const float4* __restrict__ ys,
                                                const float* __restrict__ u,
                                                const float* __restrict__ v,
                                                float4* __restrict__ outPi,
                                                float4* __restrict__ outD,
                                                float* __restrict__ rowsum)
{
    const int row = blockIdx.x;        // b*P + i
    const int b = row >> 11;
    const float4* yb = ys + (size_t)b * P;
    const float* xrow = (const float*)(ys + row);  // scaled coords of x? NO - ys is y side
    (void)xrow;

    // scaled x coords for this row come through u-side pack: we pass xs via ys ptr trick? no.
    // (handled by caller passing xs separately — see sk_final2 below)
    (void)yb; (void)u; (void)v; (void)outPi; (void)outD; (void)rowsum;
}

__global__ __launch_bounds__(256) void sk_final2(const float4* __restrict__ xs,
                                                 const float4* __restrict__ ys,
                                                 const float* __restrict__ u,
                                                 const float* __restrict__ v,
                                                 float4* __restrict__ outPi,
                                                 float4* __restrict__ outD,
                                                 float* __restrict__ rowsum)
{
    const int row = blockIdx.x;        // b*P + i
    const int b = row >> 11;

    const float4 a = xs[row];          // scaled x_i
    const float ui2 = LOG2E * u[row];  // log2-space u_i
    const float* vb = v + (size_t)b * P;
    const float4* yb = ys + (size_t)b * P;
    const size_t base4 = (size_t)row * (P / 4);

    float acc = 0.f;
    for (int t = threadIdx.x; t < P / 4; t += 256) {
        float4 dv, pv;
        float pd[4];
        #pragma unroll
        for (int c = 0; c < 4; ++c) {
            int j = 4 * t + c;
            float4 q = yb[j];
            float dx = a.x - q.x;
            float dy = a.y - q.y;
            float dz = a.z - q.z;
            float ds = __builtin_amdgcn_sqrtf(fmaf(dx, dx, fmaf(dy, dy, dz * dz))); // log2e*d
            float d = LN2 * ds;                                   // true distance
            float pi = __builtin_amdgcn_exp2f(ds + fmaf(LOG2E, vb[j], ui2)); // exp(d+u+v)
            ((float*)&dv)[c] = d;
            ((float*)&pv)[c] = pi;
            pd[c] = pi * d;
        }
        outD[base4 + t] = dv;
        outPi[base4 + t] = pv;
        acc += (pd[0] + pd[1]) + (pd[2] + pd[3]);
    }
    #pragma unroll
    for (int off = 32; off; off >>= 1) acc += __shfl_xor(acc, off);
    __shared__ float sred[4];
    if ((threadIdx.x & 63) == 0) sred[threadIdx.x >> 6] = acc;
    __syncthreads();
    if (threadIdx.x == 0) rowsum[row] = sred[0] + sred[1] + sred[2] + sred[3];
}

__global__ __launch_bounds__(256) void sk_cost(const float* __restrict__ rowsum,
                                               float* __restrict__ cost)
{
    const int b = blockIdx.x;
    float acc = 0.f;
    for (int i = threadIdx.x; i < P; i += 256) acc += rowsum[b * P + i];
    #pragma unroll
    for (int off = 32; off; off >>= 1) acc += __shfl_xor(acc, off);
    __shared__ float sred[4];
    if ((threadIdx.x & 63) == 0) sred[threadIdx.x >> 6] = acc;
    __syncthreads();
    if (threadIdx.x == 0) cost[b] = sred[0] + sred[1] + sred[2] + sred[3];
}

extern "C" void kernel_launch(void* const* d_in, const int* in_sizes, int n_in,
                              void* d_out, int out_size, void* d_ws, size_t ws_size,
                              hipStream_t stream)
{
    const float* x = (const float*)d_in[0];
    const float* y = (const float*)d_in[1];

    float* out  = (float*)d_out;
    float* cost = out;                                 // [8]
    float* pi   = out + BATCH;                         // [8*2048*2048]
    float* Dm   = pi + (size_t)BATCH * P * P;          // [8*2048*2048]

    float* u      = (float*)d_ws;                      // [8*2048]
    float* v      = u + BATCH * P;                     // [8*2048]
    float* rowsum = v + BATCH * P;                     // [8*2048]
    float4* xs    = (float4*)(rowsum + BATCH * P);     // [8*2048] float4
    float4* ys    = xs + BATCH * P;                    // [8*2048] float4

    const float logw = logf(1.0f / P);   // log_wx == log_wy (P1==P2 -> scale 1)

    sk_prep<<<BATCH * P / 256, 256, 0, stream>>>(x, y, xs, ys, u, v, logw);

    for (int it = 0; it < MAX_ITER; ++it) {
        // u update: rows = x, reduce over y/v
        sk_pass<<<BATCH * P / 16, 256, 0, stream>>>(xs, ys, v, u, logw);
        // v update: rows = y, reduce over x/u (just written)
        sk_pass<<<BATCH * P / 16, 256, 0, stream>>>(ys, xs, u, v, logw);
    }

    sk_final2<<<BATCH * P, 256, 0, stream>>>(xs, ys, u, v,
                                             (float4*)pi, (float4*)Dm, rowsum);
    sk_cost<<<BATCH, 256, 0, stream>>>(rowsum, cost);
}

// Round 3
// 2523.663 us; speedup vs baseline: 2.2532x; 1.1912x over previous
//
#include <hip/hip_runtime.h>
#include <cmath>

// Sinkhorn distance, B=8, P1=P2=2048, dim=3, EPS=1, MAX_ITER=100, THRESH=1e-9
// Outputs (flat, in return order): cost[8], pi[8*2048*2048], D[8*2048*2048]
//
// Identities:
//  - Entire iteration in log2 domain. Coords pre-scaled by log2(e):
//      d'_ij = |x'_i - y'_j|  (= log2(e) * true distance)
//    Duals stored in log2 space (u' = log2e*u). Weights: log2(1/2048) = -11.
//      u'_i = -11 - log2( sum_j exp2(v'_j) * exp2(-d'_ij) )
//    The -d' negation folds into v_exp_f32's src modifier; exp2(v'_j) is
//    pre-staged per pass, so the inner pair is 7 VALU + 2 trans ops.
//  - THRESH=1e-9 < f32 ulp of the duals (~5e-7) => convergence <=> bitwise
//    fixed point => always running 100 iterations is exactly equivalent.

constexpr int BATCH = 8;
constexpr int P = 2048;
constexpr int MAX_ITER = 100;

#define LOG2E 1.44269504088896340736f
#define LN2   0.69314718055994530942f

// Pack pre-scaled coords into float4 and init log2-space duals.
__global__ __launch_bounds__(256) void sk_prep(const float* __restrict__ x,
                                               const float* __restrict__ y,
                                               float4* __restrict__ xs,
                                               float4* __restrict__ ys,
                                               float* __restrict__ u,
                                               float* __restrict__ v)
{
    int idx = blockIdx.x * 256 + threadIdx.x;   // 0 .. BATCH*P-1
    u[idx] = 0.0f;     // log2-space u0 = 0
    v[idx] = -11.0f;   // log2-space v0 = log2(1/2048)
    xs[idx] = make_float4(LOG2E * x[3*idx], LOG2E * x[3*idx+1], LOG2E * x[3*idx+2], 0.f);
    ys[idx] = make_float4(LOG2E * y[3*idx], LOG2E * y[3*idx+1], LOG2E * y[3*idx+2], 0.f);
}

__device__ __forceinline__ void acc_pair(const float4& q, float cx, float cy, float cz,
                                         float& s)
{
    float dx = cx - q.x;
    float dy = cy - q.y;
    float dz = cz - q.z;
    float r2 = fmaf(dx, dx, fmaf(dy, dy, dz * dz));
    float d  = __builtin_amdgcn_sqrtf(r2);                 // v_sqrt_f32
    s = fmaf(q.w, __builtin_amdgcn_exp2f(-d), s);          // neg folds into v_exp src mod
}

// One half-update: dual_out[b,i] = -11 - log2( sum_j exp2(v'_j) * exp2(-d'_ij) )
// 512 thr = 8 waves; each wave owns 2 output rows; reduce side staged in LDS.
__global__ __launch_bounds__(512) void sk_pass(const float4* __restrict__ PoutS,
                                               const float4* __restrict__ PredS,
                                               const float* __restrict__ dual_red,
                                               float* __restrict__ dual_out)
{
    __shared__ float4 sh[P];          // {y0', y1', y2', exp2(v'_j)}  (32 KiB)

    const int b = blockIdx.x >> 7;                 // 128 blocks per batch
    const int rowbase = (blockIdx.x & 127) << 4;   // 16 rows per block

    const float4* pr = PredS + (size_t)b * P;
    const float* dr = dual_red + (size_t)b * P;
    for (int j = threadIdx.x; j < P; j += 512) {
        float4 c = pr[j];
        c.w = __builtin_amdgcn_exp2f(dr[j]);
        sh[j] = c;
    }
    __syncthreads();

    const int wave = threadIdx.x >> 6;
    const int lane = threadIdx.x & 63;
    const int i0 = rowbase + wave * 2;

    const float4 c0 = PoutS[(size_t)b * P + i0];
    const float4 c1 = PoutS[(size_t)b * P + i0 + 1];

    float s0 = 0.f, s1 = 0.f;
    for (int k = 0; k < P / 64; k += 4) {
        const int j = lane + (k << 6);
        float4 q0 = sh[j];
        float4 q1 = sh[j + 64];
        float4 q2 = sh[j + 128];
        float4 q3 = sh[j + 192];
        acc_pair(q0, c0.x, c0.y, c0.z, s0);
        acc_pair(q0, c1.x, c1.y, c1.z, s1);
        acc_pair(q1, c0.x, c0.y, c0.z, s0);
        acc_pair(q1, c1.x, c1.y, c1.z, s1);
        acc_pair(q2, c0.x, c0.y, c0.z, s0);
        acc_pair(q2, c1.x, c1.y, c1.z, s1);
        acc_pair(q3, c0.x, c0.y, c0.z, s0);
        acc_pair(q3, c1.x, c1.y, c1.z, s1);
    }

    #pragma unroll
    for (int off = 32; off; off >>= 1) {
        s0 += __shfl_xor(s0, off);
        s1 += __shfl_xor(s1, off);
    }

    if (lane == 0) {
        dual_out[(size_t)b * P + i0]     = -11.0f - __builtin_amdgcn_logf(s0);
        dual_out[(size_t)b * P + i0 + 1] = -11.0f - __builtin_amdgcn_logf(s1);
    }
}

// Final: D, pi = exp(D + u + v) (faithful to reference's +D sign), rowsum of pi*D.
// One block per output row; float4 loads/stores (write-bound: 268 MB).
__global__ __launch_bounds__(256) void sk_final(const float4* __restrict__ xs,
                                                const float4* __restrict__ ys,
                                                const float* __restrict__ u,
                                                const float* __restrict__ v,
                                                float4* __restrict__ outPi,
                                                float4* __restrict__ outD,
                                                float* __restrict__ rowsum)
{
    const int row = blockIdx.x;        // b*P + i
    const int b = row >> 11;

    const float4 a = xs[row];          // scaled x_i
    const float u2 = u[row];           // log2-space u_i
    const float4* vb4 = (const float4*)(v + (size_t)b * P);
    const float4* yb = ys + (size_t)b * P;
    const size_t base4 = (size_t)row * (P / 4);

    float acc = 0.f;
    for (int t = threadIdx.x; t < P / 4; t += 256) {
        float4 dv, pv;
        float4 vv = vb4[t];
        #pragma unroll
        for (int c = 0; c < 4; ++c) {
            int j = 4 * t + c;
            float4 q = yb[j];
            float dx = a.x - q.x;
            float dy = a.y - q.y;
            float dz = a.z - q.z;
            float ds = __builtin_amdgcn_sqrtf(fmaf(dx, dx, fmaf(dy, dy, dz * dz))); // log2e*d
            float d = LN2 * ds;                                        // true distance
            float pi = __builtin_amdgcn_exp2f(ds + u2 + (&vv.x)[c]);   // exp(d+u+v)
            (&dv.x)[c] = d;
            (&pv.x)[c] = pi;
            acc = fmaf(pi, d, acc);
        }
        outD[base4 + t] = dv;
        outPi[base4 + t] = pv;
    }
    #pragma unroll
    for (int off = 32; off; off >>= 1) acc += __shfl_xor(acc, off);
    __shared__ float sred[4];
    if ((threadIdx.x & 63) == 0) sred[threadIdx.x >> 6] = acc;
    __syncthreads();
    if (threadIdx.x == 0) rowsum[row] = sred[0] + sred[1] + sred[2] + sred[3];
}

__global__ __launch_bounds__(256) void sk_cost(const float* __restrict__ rowsum,
                                               float* __restrict__ cost)
{
    const int b = blockIdx.x;
    float acc = 0.f;
    for (int i = threadIdx.x; i < P; i += 256) acc += rowsum[b * P + i];
    #pragma unroll
    for (int off = 32; off; off >>= 1) acc += __shfl_xor(acc, off);
    __shared__ float sred[4];
    if ((threadIdx.x & 63) == 0) sred[threadIdx.x >> 6] = acc;
    __syncthreads();
    if (threadIdx.x == 0) cost[b] = sred[0] + sred[1] + sred[2] + sred[3];
}

extern "C" void kernel_launch(void* const* d_in, const int* in_sizes, int n_in,
                              void* d_out, int out_size, void* d_ws, size_t ws_size,
                              hipStream_t stream)
{
    const float* x = (const float*)d_in[0];
    const float* y = (const float*)d_in[1];

    float* out  = (float*)d_out;
    float* cost = out;                                 // [8]
    float* pi   = out + BATCH;                         // [8*2048*2048]
    float* Dm   = pi + (size_t)BATCH * P * P;          // [8*2048*2048]

    float* u      = (float*)d_ws;                      // [8*2048]  (log2 space)
    float* v      = u + BATCH * P;                     // [8*2048]  (log2 space)
    float* rowsum = v + BATCH * P;                     // [8*2048]
    float4* xs    = (float4*)(rowsum + BATCH * P);     // [8*2048] float4
    float4* ys    = xs + BATCH * P;                    // [8*2048] float4

    sk_prep<<<BATCH * P / 256, 256, 0, stream>>>(x, y, xs, ys, u, v);

    for (int it = 0; it < MAX_ITER; ++it) {
        // u update: rows = x, reduce over y with exp2(v')
        sk_pass<<<BATCH * P / 16, 512, 0, stream>>>(xs, ys, v, u);
        // v update: rows = y, reduce over x with exp2(u') (just written)
        sk_pass<<<BATCH * P / 16, 512, 0, stream>>>(ys, xs, u, v);
    }

    sk_final<<<BATCH * P, 256, 0, stream>>>(xs, ys, u, v,
                                            (float4*)pi, (float4*)Dm, rowsum);
    sk_cost<<<BATCH, 256, 0, stream>>>(rowsum, cost);
}

// Round 4
// 2418.053 us; speedup vs baseline: 2.3516x; 1.0437x over previous
//
#include <hip/hip_runtime.h>
#include <cmath>

// Sinkhorn distance, B=8, P1=P2=2048, dim=3, EPS=1, MAX_ITER=100, THRESH=1e-9
// Outputs (flat, in return order): cost[8], pi[8*2048*2048], D[8*2048*2048]
//
// Identities:
//  - Entire iteration in log2 domain. Coords pre-scaled by log2(e):
//      d'_ij = |x'_i - y'_j|  (= log2(e) * true distance)
//    Duals kept in log2 space. Weights: log2(1/2048) = -11 exactly.
//      u'_i = -11 - log2( sum_j exp2(v'_j) * exp2(-d'_ij) )
//  - THRESH=1e-9 < f32 ulp of the duals (~5e-7) => convergence <=> bitwise
//    fixed point => always running 100 iterations is exactly equivalent.
//  - Inner loop packed 2 j's/lane via ext_vector_type(2) float -> v_pk_* ops;
//    LDS is SoA float2 so packed operands land in adjacent VGPRs directly.

constexpr int BATCH = 8;
constexpr int P = 2048;
constexpr int MAX_ITER = 100;

#define LOG2E 1.44269504088896340736f
#define LN2   0.69314718055994530942f

typedef __attribute__((ext_vector_type(2))) float v2f;

static __device__ __forceinline__ v2f mkv2(float a, float b) { v2f r; r.x = a; r.y = b; return r; }

// Pack pre-scaled coords into float4 and init log2-space duals.
__global__ __launch_bounds__(256) void sk_prep(const float* __restrict__ x,
                                               const float* __restrict__ y,
                                               float4* __restrict__ xs,
                                               float4* __restrict__ ys,
                                               float* __restrict__ u,
                                               float* __restrict__ v)
{
    int idx = blockIdx.x * 256 + threadIdx.x;   // 0 .. BATCH*P-1
    u[idx] = 0.0f;     // log2-space u0 = 0
    v[idx] = -11.0f;   // log2-space v0 = log2(1/2048)
    xs[idx] = make_float4(LOG2E * x[3*idx], LOG2E * x[3*idx+1], LOG2E * x[3*idx+2], 0.f);
    ys[idx] = make_float4(LOG2E * y[3*idx], LOG2E * y[3*idx+1], LOG2E * y[3*idx+2], 0.f);
}

// One half-update: dual_out[b,i] = -11 - log2( sum_j exp2(v'_j) * exp2(-d'_ij) )
// 256 thr = 4 waves; each wave owns 4 output rows (each LDS read feeds 4 pairs).
__global__ __launch_bounds__(256, 4) void sk_pass(const float4* __restrict__ PoutS,
                                                  const float4* __restrict__ PredS,
                                                  const float* __restrict__ dual_red,
                                                  float* __restrict__ dual_out)
{
    __shared__ v2f shx[P/2], shy[P/2], shz[P/2], shw[P/2];   // SoA, 32 KiB

    const int b = blockIdx.x >> 7;                 // 128 blocks per batch
    const int rowbase = (blockIdx.x & 127) << 4;   // 16 rows per block

    const float4* pr = PredS + (size_t)b * P;
    const v2f* dr = (const v2f*)(dual_red + (size_t)b * P);
    for (int t = threadIdx.x; t < P/2; t += 256) {
        float4 c0 = pr[2*t];
        float4 c1 = pr[2*t + 1];
        v2f dd = dr[t];
        shx[t] = mkv2(c0.x, c1.x);
        shy[t] = mkv2(c0.y, c1.y);
        shz[t] = mkv2(c0.z, c1.z);
        shw[t] = mkv2(__builtin_amdgcn_exp2f(dd.x), __builtin_amdgcn_exp2f(dd.y));
    }
    __syncthreads();

    const int wave = threadIdx.x >> 6;
    const int lane = threadIdx.x & 63;
    const int i0 = rowbase + wave * 4;

    float cx[4], cy[4], cz[4];
    #pragma unroll
    for (int r = 0; r < 4; ++r) {
        float4 c = PoutS[(size_t)b * P + i0 + r];
        cx[r] = c.x; cy[r] = c.y; cz[r] = c.z;
    }

    v2f a0 = mkv2(0.f, 0.f), a1 = a0, a2 = a0, a3 = a0;

    #pragma unroll 4
    for (int k = 0; k < 16; ++k) {
        const int t = lane + (k << 6);
        v2f X = shx[t];
        v2f Y = shy[t];
        v2f Z = shz[t];
        v2f W = shw[t];
        #pragma unroll
        for (int r = 0; r < 4; ++r) {
            v2f dx = X - cx[r];                    // v_pk_add_f32 (neg mod)
            v2f dy = Y - cy[r];
            v2f dz = Z - cz[r];
            v2f r2 = dx*dx + dy*dy + dz*dz;        // v_pk_fma_f32 chain
            v2f e;
            e.x = __builtin_amdgcn_exp2f(-__builtin_amdgcn_sqrtf(r2.x));
            e.y = __builtin_amdgcn_exp2f(-__builtin_amdgcn_sqrtf(r2.y));
            v2f* acc = (r == 0) ? &a0 : (r == 1) ? &a1 : (r == 2) ? &a2 : &a3;
            *acc += W * e;                         // v_pk_fma_f32
        }
    }

    v2f accs[4] = {a0, a1, a2, a3};
    #pragma unroll
    for (int r = 0; r < 4; ++r) {
        float s = accs[r].x + accs[r].y;
        #pragma unroll
        for (int off = 32; off; off >>= 1) s += __shfl_xor(s, off);
        if (lane == 0)
            dual_out[(size_t)b * P + i0 + r] = -11.0f - __builtin_amdgcn_logf(s);
    }
}

// Final: D, pi = exp(D + u + v) (faithful to reference's +D sign), rowsum of pi*D.
// One block per output row; float4 loads/stores (write-bound: 268 MB).
__global__ __launch_bounds__(256) void sk_final(const float4* __restrict__ xs,
                                                const float4* __restrict__ ys,
                                                const float* __restrict__ u,
                                                const float* __restrict__ v,
                                                float4* __restrict__ outPi,
                                                float4* __restrict__ outD,
                                                float* __restrict__ rowsum)
{
    const int row = blockIdx.x;        // b*P + i
    const int b = row >> 11;

    const float4 a = xs[row];          // scaled x_i
    const float u2 = u[row];           // log2-space u_i
    const float4* vb4 = (const float4*)(v + (size_t)b * P);
    const float4* yb = ys + (size_t)b * P;
    const size_t base4 = (size_t)row * (P / 4);

    float acc = 0.f;
    for (int t = threadIdx.x; t < P / 4; t += 256) {
        float4 dv, pv;
        float4 vv = vb4[t];
        #pragma unroll
        for (int c = 0; c < 4; ++c) {
            int j = 4 * t + c;
            float4 q = yb[j];
            float dx = a.x - q.x;
            float dy = a.y - q.y;
            float dz = a.z - q.z;
            float ds = __builtin_amdgcn_sqrtf(fmaf(dx, dx, fmaf(dy, dy, dz * dz))); // log2e*d
            float d = LN2 * ds;                                        // true distance
            float pi = __builtin_amdgcn_exp2f(ds + u2 + (&vv.x)[c]);   // exp(d+u+v)
            (&dv.x)[c] = d;
            (&pv.x)[c] = pi;
            acc = fmaf(pi, d, acc);
        }
        outD[base4 + t] = dv;
        outPi[base4 + t] = pv;
    }
    #pragma unroll
    for (int off = 32; off; off >>= 1) acc += __shfl_xor(acc, off);
    __shared__ float sred[4];
    if ((threadIdx.x & 63) == 0) sred[threadIdx.x >> 6] = acc;
    __syncthreads();
    if (threadIdx.x == 0) rowsum[row] = sred[0] + sred[1] + sred[2] + sred[3];
}

__global__ __launch_bounds__(256) void sk_cost(const float* __restrict__ rowsum,
                                               float* __restrict__ cost)
{
    const int b = blockIdx.x;
    float acc = 0.f;
    for (int i = threadIdx.x; i < P; i += 256) acc += rowsum[b * P + i];
    #pragma unroll
    for (int off = 32; off; off >>= 1) acc += __shfl_xor(acc, off);
    __shared__ float sred[4];
    if ((threadIdx.x & 63) == 0) sred[threadIdx.x >> 6] = acc;
    __syncthreads();
    if (threadIdx.x == 0) cost[b] = sred[0] + sred[1] + sred[2] + sred[3];
}

extern "C" void kernel_launch(void* const* d_in, const int* in_sizes, int n_in,
                              void* d_out, int out_size, void* d_ws, size_t ws_size,
                              hipStream_t stream)
{
    const float* x = (const float*)d_in[0];
    const float* y = (const float*)d_in[1];

    float* out  = (float*)d_out;
    float* cost = out;                                 // [8]
    float* pi   = out + BATCH;                         // [8*2048*2048]
    float* Dm   = pi + (size_t)BATCH * P * P;          // [8*2048*2048]

    float* u      = (float*)d_ws;                      // [8*2048]  (log2 space)
    float* v      = u + BATCH * P;                     // [8*2048]  (log2 space)
    float* rowsum = v + BATCH * P;                     // [8*2048]
    float4* xs    = (float4*)(rowsum + BATCH * P);     // [8*2048] float4
    float4* ys    = xs + BATCH * P;                    // [8*2048] float4

    sk_prep<<<BATCH * P / 256, 256, 0, stream>>>(x, y, xs, ys, u, v);

    for (int it = 0; it < MAX_ITER; ++it) {
        // u update: rows = x, reduce over y with exp2(v')
        sk_pass<<<BATCH * P / 16, 256, 0, stream>>>(xs, ys, v, u);
        // v update: rows = y, reduce over x with exp2(u') (just written)
        sk_pass<<<BATCH * P / 16, 256, 0, stream>>>(ys, xs, u, v);
    }

    sk_final<<<BATCH * P, 256, 0, stream>>>(xs, ys, u, v,
                                            (float4*)pi, (float4*)Dm, rowsum);
    sk_cost<<<BATCH, 256, 0, stream>>>(rowsum, cost);
}

// Round 5
// 2365.092 us; speedup vs baseline: 2.4043x; 1.0224x over previous
//
#include <hip/hip_runtime.h>
#include <cmath>

// Sinkhorn distance, B=8, P1=P2=2048, dim=3, EPS=1, MAX_ITER=100, THRESH=1e-9
// Outputs (flat, in return order): cost[8], pi[8*2048*2048], D[8*2048*2048]
//
// Identities:
//  - Entire iteration in log2 domain. Coords pre-scaled by log2(e):
//      d'_ij = |x'_i - y'_j|  (= log2(e) * true distance)
//    Duals kept in log2 space. Weights: log2(1/2048) = -11 exactly.
//      u'_i = -11 - log2( sum_j exp2(v'_j) * exp2(-d'_ij) )
//  - THRESH=1e-9 < f32 ulp of the duals (~5e-7) => convergence <=> bitwise
//    fixed point => always running 100 iterations is exactly equivalent.
//  - Inner loop packed 2 j's/lane (ext_vector_type(2) -> v_pk_* f32 ops).
//  - Occupancy: rows/wave fixes total waves (waves = rows/R). R=4 gave only
//    4 waves/SIMD -> trans pipe starved by the sub->fma->sqrt->exp chain.
//    j-split: 8 waves/block, waves 0-3 do j<1024, waves 4-7 do j>=1024,
//    each wave keeps 4 rows -> 8 waves/SIMD, same LDS amortization.

constexpr int BATCH = 8;
constexpr int P = 2048;
constexpr int MAX_ITER = 100;

#define LOG2E 1.44269504088896340736f
#define LN2   0.69314718055994530942f

typedef __attribute__((ext_vector_type(2))) float v2f;

static __device__ __forceinline__ v2f mkv2(float a, float b) { v2f r; r.x = a; r.y = b; return r; }

// Pack pre-scaled coords into float4 and init log2-space duals.
__global__ __launch_bounds__(256) void sk_prep(const float* __restrict__ x,
                                               const float* __restrict__ y,
                                               float4* __restrict__ xs,
                                               float4* __restrict__ ys,
                                               float* __restrict__ u,
                                               float* __restrict__ v)
{
    int idx = blockIdx.x * 256 + threadIdx.x;   // 0 .. BATCH*P-1
    u[idx] = 0.0f;     // log2-space u0 = 0
    v[idx] = -11.0f;   // log2-space v0 = log2(1/2048)
    xs[idx] = make_float4(LOG2E * x[3*idx], LOG2E * x[3*idx+1], LOG2E * x[3*idx+2], 0.f);
    ys[idx] = make_float4(LOG2E * y[3*idx], LOG2E * y[3*idx+1], LOG2E * y[3*idx+2], 0.f);
}

// One half-update: dual_out[b,i] = -11 - log2( sum_j exp2(v'_j) * exp2(-d'_ij) )
// 512 thr = 8 waves; wave = (half h, quad q): rows i0=rowbase+4q, j in [512h*2, ...).
__global__ __launch_bounds__(512, 8) void sk_pass(const float4* __restrict__ PoutS,
                                                  const float4* __restrict__ PredS,
                                                  const float* __restrict__ dual_red,
                                                  float* __restrict__ dual_out)
{
    __shared__ v2f shx[P/2], shy[P/2], shz[P/2], shw[P/2];   // SoA, 32 KiB
    __shared__ float wpart[8][4];

    const int b = blockIdx.x >> 7;                 // 128 blocks per batch
    const int rowbase = (blockIdx.x & 127) << 4;   // 16 rows per block

    const float4* pr = PredS + (size_t)b * P;
    const v2f* dr = (const v2f*)(dual_red + (size_t)b * P);
    #pragma unroll
    for (int it = 0; it < 2; ++it) {
        int t = threadIdx.x + it * 512;            // 0 .. 1023
        float4 c0 = pr[2*t];
        float4 c1 = pr[2*t + 1];
        v2f dd = dr[t];
        shx[t] = mkv2(c0.x, c1.x);
        shy[t] = mkv2(c0.y, c1.y);
        shz[t] = mkv2(c0.z, c1.z);
        shw[t] = mkv2(__builtin_amdgcn_exp2f(dd.x), __builtin_amdgcn_exp2f(dd.y));
    }
    __syncthreads();

    const int wave = threadIdx.x >> 6;
    const int lane = threadIdx.x & 63;
    const int quad = wave & 3;                     // which 4-row group
    const int half = wave >> 2;                    // which j half-range
    const int i0 = rowbase + quad * 4;
    const int tbase = half * 512 + lane;           // v2f index

    float cx[4], cy[4], cz[4];
    #pragma unroll
    for (int r = 0; r < 4; ++r) {
        float4 c = PoutS[(size_t)b * P + i0 + r];
        cx[r] = c.x; cy[r] = c.y; cz[r] = c.z;
    }

    v2f acc[4];
    #pragma unroll
    for (int r = 0; r < 4; ++r) acc[r] = mkv2(0.f, 0.f);

    #pragma unroll 4
    for (int k = 0; k < 8; ++k) {
        const int t = tbase + (k << 6);
        v2f X = shx[t];
        v2f Y = shy[t];
        v2f Z = shz[t];
        v2f W = shw[t];
        #pragma unroll
        for (int r = 0; r < 4; ++r) {
            v2f dx = X - cx[r];                    // v_pk_add_f32 (neg mod)
            v2f dy = Y - cy[r];
            v2f dz = Z - cz[r];
            v2f r2 = dx*dx + dy*dy + dz*dz;        // v_pk_fma_f32 chain
            v2f e;
            e.x = __builtin_amdgcn_exp2f(-__builtin_amdgcn_sqrtf(r2.x));
            e.y = __builtin_amdgcn_exp2f(-__builtin_amdgcn_sqrtf(r2.y));
            acc[r] += W * e;                       // v_pk_fma_f32
        }
    }

    #pragma unroll
    for (int r = 0; r < 4; ++r) {
        float s = acc[r].x + acc[r].y;
        #pragma unroll
        for (int off = 32; off; off >>= 1) s += __shfl_xor(s, off);
        if (lane == 0) wpart[wave][r] = s;
    }
    __syncthreads();

    if (threadIdx.x < 16) {
        const int q = threadIdx.x >> 2;
        const int ri = threadIdx.x & 3;
        float s = wpart[q][ri] + wpart[q + 4][ri];
        dual_out[(size_t)b * P + rowbase + threadIdx.x] = -11.0f - __builtin_amdgcn_logf(s);
    }
}

// Final: D, pi = exp(D + u + v) (faithful to reference's +D sign), rowsum of pi*D.
// One block per output row; float4 loads/stores (write-bound: 268 MB).
__global__ __launch_bounds__(256) void sk_final(const float4* __restrict__ xs,
                                                const float4* __restrict__ ys,
                                                const float* __restrict__ u,
                                                const float* __restrict__ v,
                                                float4* __restrict__ outPi,
                                                float4* __restrict__ outD,
                                                float* __restrict__ rowsum)
{
    const int row = blockIdx.x;        // b*P + i
    const int b = row >> 11;

    const float4 a = xs[row];          // scaled x_i
    const float u2 = u[row];           // log2-space u_i
    const float4* vb4 = (const float4*)(v + (size_t)b * P);
    const float4* yb = ys + (size_t)b * P;
    const size_t base4 = (size_t)row * (P / 4);

    float acc = 0.f;
    for (int t = threadIdx.x; t < P / 4; t += 256) {
        float4 dv, pv;
        float4 vv = vb4[t];
        #pragma unroll
        for (int c = 0; c < 4; ++c) {
            int j = 4 * t + c;
            float4 q = yb[j];
            float dx = a.x - q.x;
            float dy = a.y - q.y;
            float dz = a.z - q.z;
            float ds = __builtin_amdgcn_sqrtf(fmaf(dx, dx, fmaf(dy, dy, dz * dz))); // log2e*d
            float d = LN2 * ds;                                        // true distance
            float pi = __builtin_amdgcn_exp2f(ds + u2 + (&vv.x)[c]);   // exp(d+u+v)
            (&dv.x)[c] = d;
            (&pv.x)[c] = pi;
            acc = fmaf(pi, d, acc);
        }
        outD[base4 + t] = dv;
        outPi[base4 + t] = pv;
    }
    #pragma unroll
    for (int off = 32; off; off >>= 1) acc += __shfl_xor(acc, off);
    __shared__ float sred[4];
    if ((threadIdx.x & 63) == 0) sred[threadIdx.x >> 6] = acc;
    __syncthreads();
    if (threadIdx.x == 0) rowsum[row] = sred[0] + sred[1] + sred[2] + sred[3];
}

__global__ __launch_bounds__(256) void sk_cost(const float* __restrict__ rowsum,
                                               float* __restrict__ cost)
{
    const int b = blockIdx.x;
    float acc = 0.f;
    for (int i = threadIdx.x; i < P; i += 256) acc += rowsum[b * P + i];
    #pragma unroll
    for (int off = 32; off; off >>= 1) acc += __shfl_xor(acc, off);
    __shared__ float sred[4];
    if ((threadIdx.x & 63) == 0) sred[threadIdx.x >> 6] = acc;
    __syncthreads();
    if (threadIdx.x == 0) cost[b] = sred[0] + sred[1] + sred[2] + sred[3];
}

extern "C" void kernel_launch(void* const* d_in, const int* in_sizes, int n_in,
                              void* d_out, int out_size, void* d_ws, size_t ws_size,
                              hipStream_t stream)
{
    const float* x = (const float*)d_in[0];
    const float* y = (const float*)d_in[1];

    float* out  = (float*)d_out;
    float* cost = out;                                 // [8]
    float* pi   = out + BATCH;                         // [8*2048*2048]
    float* Dm   = pi + (size_t)BATCH * P * P;          // [8*2048*2048]

    float* u      = (float*)d_ws;                      // [8*2048]  (log2 space)
    float* v      = u + BATCH * P;                     // [8*2048]  (log2 space)
    float* rowsum = v + BATCH * P;                     // [8*2048]
    float4* xs    = (float4*)(rowsum + BATCH * P);     // [8*2048] float4
    float4* ys    = xs + BATCH * P;                    // [8*2048] float4

    sk_prep<<<BATCH * P / 256, 256, 0, stream>>>(x, y, xs, ys, u, v);

    for (int it = 0; it < MAX_ITER; ++it) {
        // u update: rows = x, reduce over y with exp2(v')
        sk_pass<<<BATCH * P / 16, 512, 0, stream>>>(xs, ys, v, u);
        // v update: rows = y, reduce over x with exp2(u') (just written)
        sk_pass<<<BATCH * P / 16, 512, 0, stream>>>(ys, xs, u, v);
    }

    sk_final<<<BATCH * P, 256, 0, stream>>>(xs, ys, u, v,
                                            (float4*)pi, (float4*)Dm, rowsum);
    sk_cost<<<BATCH, 256, 0, stream>>>(rowsum, cost);
}